// Round 18
// baseline (213.289 us; speedup 1.0000x reference)
//
#include <hip/hip_runtime.h>
#include <math.h>

// ---------------------------------------------------------------------------
// StageA GNN: pack -> MFMA-enc(+proj0) -> CSR(rank-hist, atomic-free scatter)
// -> L x (gateagg -> MFMA-upd(+proj1 | +outhead)) -> done.
// R18: (a) gateagg writes normalized bf16 neigh (nb) -> upd loses its whole
// staging prologue + barrier (A-fragments load straight from nb, bit-identical
// values); (b) fp32 h buffer deleted -- residual reads bf16 h from ahb (every
// h producer already writes it); (c) upd has zero barriers (per-wave tls).
// ---------------------------------------------------------------------------

typedef unsigned short ushort_t;
typedef __attribute__((ext_vector_type(8))) short bf16x8;
typedef __attribute__((ext_vector_type(4))) float f32x4;

__device__ __forceinline__ float bf2f(ushort_t u) {
    return __uint_as_float(((unsigned int)u) << 16);
}
__device__ __forceinline__ ushort_t f2bf(float f) {
    unsigned int x = __float_as_uint(f);
    unsigned int lsb = (x >> 16) & 1u;
    x += 0x7fffu + lsb;                 // round-to-nearest-even
    return (ushort_t)(x >> 16);
}

// pack all weights into MFMA B-fragment order (bf16).
// fragment: elem i of lane l = B[k = kb*32 + (l>>4)*8 + i][n = nt*16 + (l&15)]
__global__ __launch_bounds__(256) void pack_kernel(
    const float* __restrict__ w1, const float* __restrict__ w2,
    const float* __restrict__ gw1, const float* __restrict__ uw1,
    const float* __restrict__ uw2, const float* __restrict__ tw,
    ushort_t* __restrict__ w1f, ushort_t* __restrict__ w2f,
    ushort_t* __restrict__ g1f, ushort_t* __restrict__ u1f,
    ushort_t* __restrict__ u2f, ushort_t* __restrict__ tuf) {
    int t = blockIdx.x * 256 + threadIdx.x;
    if (t < 16384) {   // w1f: nt(4) kb(8) lane(64) i(8)
        int i = t & 7, l = (t >> 3) & 63, kb = (t >> 9) & 7, nt = t >> 12;
        int k = kb * 32 + (l >> 4) * 8 + i, n = nt * 16 + (l & 15);
        w1f[t] = f2bf(w1[(size_t)k * 64 + n]);
    }
    if (t < 4096) {    // w2f: nt(4) kb(2)
        int i = t & 7, l = (t >> 3) & 63, kb = (t >> 9) & 1, nt = t >> 10;
        int k = kb * 32 + (l >> 4) * 8 + i, n = nt * 16 + (l & 15);
        w2f[t] = f2bf(w2[(size_t)k * 64 + n]);
    }
    if (t < 8192) {    // g1f: j(8)=part*4+nt, kb(2); gw1 is [128][64]
        int i = t & 7, l = (t >> 3) & 63, kb = (t >> 9) & 1, j = t >> 10;
        int part = j >> 2, nt = j & 3;
        int k = part * 64 + kb * 32 + (l >> 4) * 8 + i, n = nt * 16 + (l & 15);
        g1f[t] = f2bf(gw1[(size_t)k * 64 + n]);
    }
    if (t < 8192) {    // u1f/u2f: layer(2) nt(4) kb(2)
        int i = t & 7, l = (t >> 3) & 63, kb = (t >> 9) & 1;
        int nt = (t >> 10) & 3, lay = t >> 12;
        int k = kb * 32 + (l >> 4) * 8 + i, n = nt * 16 + (l & 15);
        u1f[t] = f2bf(uw1[(size_t)lay * 4096 + (size_t)k * 64 + n]);
        u2f[t] = f2bf(uw2[(size_t)lay * 4096 + (size_t)k * 64 + n]);
    }
    if (t < 2048) {    // tuf: nt(2) kb(2); toU_w is [64][32]
        int i = t & 7, l = (t >> 3) & 63, kb = (t >> 9) & 1, nt = t >> 10;
        int k = kb * 32 + (l >> 4) * 8 + i, n = nt * 16 + (l & 15);
        tuf[t] = f2bf(tw[(size_t)k * 32 + n]);
    }
}

// MFMA encoder + fused layer-0 gate projection (no fp32 h output).
__global__ __launch_bounds__(256) void enc_kernel(
    const float* __restrict__ x, const ushort_t* __restrict__ w1f,
    const float* __restrict__ b1, const ushort_t* __restrict__ w2f,
    const float* __restrict__ b2, const ushort_t* __restrict__ g1f,
    const float* __restrict__ gb1,
    ushort_t* __restrict__ ahb, float* __restrict__ bbuf, int N) {
    __shared__ ushort_t xls[4][16][264];
    __shared__ ushort_t tls[4][16][72];
    const int tid  = threadIdx.x;
    const int lane = tid & 63;
    const int w    = tid >> 6;
    const int m    = lane & 15;
    const int g    = lane >> 4;
    const int rbase = blockIdx.x * 64;
    for (int p = tid; p < 64 * 64; p += 256) {
        int row = p >> 6, k4 = p & 63;
        int grow = rbase + row;
        float4 v = (grow < N) ? *(const float4*)(x + (size_t)grow * 256 + k4 * 4)
                              : make_float4(0.f, 0.f, 0.f, 0.f);
        unsigned int p0 = (unsigned int)f2bf(v.x) | ((unsigned int)f2bf(v.y) << 16);
        unsigned int p1 = (unsigned int)f2bf(v.z) | ((unsigned int)f2bf(v.w) << 16);
        *(uint2*)&xls[row >> 4][row & 15][k4 * 4] = make_uint2(p0, p1);
    }
    __syncthreads();
    f32x4 acc[4] = {{0,0,0,0},{0,0,0,0},{0,0,0,0},{0,0,0,0}};
    #pragma unroll
    for (int kb = 0; kb < 8; ++kb) {
        bf16x8 a = *(const bf16x8*)&xls[w][m][kb * 32 + g * 8];
        #pragma unroll
        for (int nt = 0; nt < 4; ++nt) {
            bf16x8 b = *(const bf16x8*)(w1f + (((size_t)nt * 8 + kb) * 64 + lane) * 8);
            acc[nt] = __builtin_amdgcn_mfma_f32_16x16x32_bf16(a, b, acc[nt], 0, 0, 0);
        }
    }
    #pragma unroll
    for (int nt = 0; nt < 4; ++nt) {
        float bb1 = b1[nt * 16 + m];
        #pragma unroll
        for (int r = 0; r < 4; ++r) {
            float tv = fmaxf(acc[nt][r] + bb1, 0.f);
            tls[w][g * 4 + r][nt * 16 + m] = f2bf(tv);
        }
    }
    f32x4 acc2[4] = {{0,0,0,0},{0,0,0,0},{0,0,0,0},{0,0,0,0}};
    #pragma unroll
    for (int kb = 0; kb < 2; ++kb) {
        bf16x8 a2 = *(const bf16x8*)&tls[w][m][kb * 32 + g * 8];
        #pragma unroll
        for (int nt = 0; nt < 4; ++nt) {
            bf16x8 b = *(const bf16x8*)(w2f + (((size_t)nt * 2 + kb) * 64 + lane) * 8);
            acc2[nt] = __builtin_amdgcn_mfma_f32_16x16x32_bf16(a2, b, acc2[nt], 0, 0, 0);
        }
    }
    // bf16 h into ahb + tls (for proj A-fragments)
    #pragma unroll
    for (int nt = 0; nt < 4; ++nt) {
        float bb2 = b2[nt * 16 + m];
        #pragma unroll
        for (int r = 0; r < 4; ++r) {
            float hv = fmaxf(acc2[nt][r] + bb2, 0.f);
            int grow = rbase + w * 16 + g * 4 + r;
            ushort_t hb = f2bf(hv);
            tls[w][g * 4 + r][nt * 16 + m] = hb;
            if (grow < N)
                ahb[(size_t)grow * 128 + 64 + nt * 16 + m] = hb;
        }
    }
    // layer-0 gate projection: [a|b] = h @ gw1
    f32x4 accp[8] = {{0,0,0,0},{0,0,0,0},{0,0,0,0},{0,0,0,0},
                     {0,0,0,0},{0,0,0,0},{0,0,0,0},{0,0,0,0}};
    #pragma unroll
    for (int kb = 0; kb < 2; ++kb) {
        bf16x8 a3 = *(const bf16x8*)&tls[w][m][kb * 32 + g * 8];
        #pragma unroll
        for (int j = 0; j < 8; ++j) {
            bf16x8 b = *(const bf16x8*)(g1f + (((size_t)j * 2 + kb) * 64 + lane) * 8);
            accp[j] = __builtin_amdgcn_mfma_f32_16x16x32_bf16(a3, b, accp[j], 0, 0, 0);
        }
    }
    #pragma unroll
    for (int nt = 0; nt < 4; ++nt) {
        float gbl = gb1[nt * 16 + m];
        #pragma unroll
        for (int r = 0; r < 4; ++r) {
            int grow = rbase + w * 16 + g * 4 + r;
            if (grow < N) {
                ahb[(size_t)grow * 128 + nt * 16 + m] = f2bf(accp[nt][r] + gbl);
                bbuf[(size_t)grow * 64 + nt * 16 + m] = accp[nt + 4][r];
            }
        }
    }
}

// ---- CSR build ----
__global__ __launch_bounds__(256) void hist_kernel(
    const int* __restrict__ dst, int* __restrict__ cnt,
    int* __restrict__ rank, int E) {
    for (int e = blockIdx.x * blockDim.x + threadIdx.x; e < E;
         e += gridDim.x * blockDim.x)
        rank[e] = atomicAdd(&cnt[dst[e]], 1);
}

__global__ __launch_bounds__(256) void scan1_kernel(
    const int* __restrict__ cnt, int* __restrict__ bsum, int N) {
    __shared__ int red[256];
    int i = blockIdx.x * 256 + threadIdx.x;
    red[threadIdx.x] = (i < N) ? cnt[i] : 0;
    __syncthreads();
    for (int off = 128; off > 0; off >>= 1) {
        if (threadIdx.x < off) red[threadIdx.x] += red[threadIdx.x + off];
        __syncthreads();
    }
    if (threadIdx.x == 0) bsum[blockIdx.x] = red[0];
}

__global__ __launch_bounds__(1024) void scan2_kernel(
    int* __restrict__ bsum, int nb) {
    __shared__ int s[1024];
    int v = (threadIdx.x < nb) ? bsum[threadIdx.x] : 0;
    s[threadIdx.x] = v;
    __syncthreads();
    for (int off = 1; off < 1024; off <<= 1) {
        int t = (threadIdx.x >= off) ? s[threadIdx.x - off] : 0;
        __syncthreads();
        s[threadIdx.x] += t;
        __syncthreads();
    }
    if (threadIdx.x < nb) bsum[threadIdx.x] = s[threadIdx.x] - v;  // exclusive
}

__global__ __launch_bounds__(256) void scan3_kernel(
    const int* __restrict__ cnt, const int* __restrict__ bsum,
    int* __restrict__ row_ptr, int N) {
    __shared__ int s[256];
    int i = blockIdx.x * 256 + threadIdx.x;
    int v = (i < N) ? cnt[i] : 0;
    s[threadIdx.x] = v;
    __syncthreads();
    for (int off = 1; off < 256; off <<= 1) {
        int t = (threadIdx.x >= off) ? s[threadIdx.x - off] : 0;
        __syncthreads();
        s[threadIdx.x] += t;
        __syncthreads();
    }
    if (i < N) row_ptr[i] = bsum[blockIdx.x] + s[threadIdx.x] - v;  // exclusive
    if (i == N - 1) row_ptr[N] = bsum[blockIdx.x] + s[threadIdx.x]; // total
}

// atomic-free scatter: pos = row_ptr[dst] + rank (precomputed in hist)
__global__ __launch_bounds__(256) void scatter_kernel(
    const int* __restrict__ src, const int* __restrict__ dst,
    const float* __restrict__ base_w, const float* __restrict__ rr,
    const int* __restrict__ row_ptr, const int* __restrict__ rank,
    int2* __restrict__ recs, int E) {
    for (int e = blockIdx.x * blockDim.x + threadIdx.x; e < E;
         e += gridDim.x * blockDim.x) {
        int s = src[e], d = dst[e];
        int pos = row_ptr[d] + rank[e];
        float rs = 1.f / (1.f + __expf(-rr[s]));
        float rd = 1.f / (1.f + __expf(-rr[d]));
        float c = base_w[e] * rs * rd;
        recs[pos] = make_int2(s, __float_as_int(c));
    }
}

// fused gate + aggregation: wave-per-node, 16-lane group/edge.
// Writes normalized bf16 neigh rows (nb) -- upd stages nothing.
__global__ __launch_bounds__(256) void gateagg_kernel(
    const int* __restrict__ row_ptr, const int2* __restrict__ recs,
    const ushort_t* __restrict__ ahb, const float* __restrict__ bb,
    const float* __restrict__ gw2, const float* __restrict__ gb2,
    ushort_t* __restrict__ nb, int N) {
    const int lane = threadIdx.x & 63;
    const int sub  = lane & 15;
    const int grp  = lane >> 4;
    const float4 gv = ((const float4*)gw2)[sub];
    const float gb = gb2[0];
    const int wid  = blockIdx.x * (blockDim.x >> 6) + (threadIdx.x >> 6);
    const int nw   = gridDim.x * (blockDim.x >> 6);
    for (int n = wid; n < N; n += nw) {
        const int beg = row_ptr[n], end = row_ptr[n + 1];
        const float4 bv = *(const float4*)(bb + (size_t)n * 64 + sub * 4);
        float m0 = 0.f, m1 = 0.f, m2 = 0.f, m3 = 0.f, dacc = 0.f;
        int i = beg + grp;
        for (; i + 4 < end; i += 8) {
            int2 rA = recs[i];
            int2 rB = recs[i + 4];
            const ushort_t* rowA = ahb + (size_t)rA.x * 128;
            const ushort_t* rowB = ahb + (size_t)rB.x * 128;
            ushort4 avA = *(const ushort4*)(rowA + sub * 4);
            ushort4 hvA = *(const ushort4*)(rowA + 64 + sub * 4);
            ushort4 avB = *(const ushort4*)(rowB + sub * 4);
            ushort4 hvB = *(const ushort4*)(rowB + 64 + sub * 4);
            float tA = fmaxf(bf2f(avA.x) + bv.x, 0.f) * gv.x
                     + fmaxf(bf2f(avA.y) + bv.y, 0.f) * gv.y
                     + fmaxf(bf2f(avA.z) + bv.z, 0.f) * gv.z
                     + fmaxf(bf2f(avA.w) + bv.w, 0.f) * gv.w;
            float tB = fmaxf(bf2f(avB.x) + bv.x, 0.f) * gv.x
                     + fmaxf(bf2f(avB.y) + bv.y, 0.f) * gv.y
                     + fmaxf(bf2f(avB.z) + bv.z, 0.f) * gv.z
                     + fmaxf(bf2f(avB.w) + bv.w, 0.f) * gv.w;
            #pragma unroll
            for (int o = 8; o > 0; o >>= 1) {
                tA += __shfl_xor(tA, o, 64);
                tB += __shfl_xor(tB, o, 64);
            }
            float wA = __int_as_float(rA.y) / (1.f + __expf(-(tA + gb)));
            float wB = __int_as_float(rB.y) / (1.f + __expf(-(tB + gb)));
            m0 = fmaf(wA, bf2f(hvA.x), m0); m0 = fmaf(wB, bf2f(hvB.x), m0);
            m1 = fmaf(wA, bf2f(hvA.y), m1); m1 = fmaf(wB, bf2f(hvB.y), m1);
            m2 = fmaf(wA, bf2f(hvA.z), m2); m2 = fmaf(wB, bf2f(hvB.z), m2);
            m3 = fmaf(wA, bf2f(hvA.w), m3); m3 = fmaf(wB, bf2f(hvB.w), m3);
            dacc += wA + wB;
        }
        if (i < end) {
            int2 r = recs[i];
            const ushort_t* row = ahb + (size_t)r.x * 128;
            ushort4 av = *(const ushort4*)(row + sub * 4);
            ushort4 hv = *(const ushort4*)(row + 64 + sub * 4);
            float t = fmaxf(bf2f(av.x) + bv.x, 0.f) * gv.x
                    + fmaxf(bf2f(av.y) + bv.y, 0.f) * gv.y
                    + fmaxf(bf2f(av.z) + bv.z, 0.f) * gv.z
                    + fmaxf(bf2f(av.w) + bv.w, 0.f) * gv.w;
            #pragma unroll
            for (int o = 8; o > 0; o >>= 1) t += __shfl_xor(t, o, 64);
            float w = __int_as_float(r.y) / (1.f + __expf(-(t + gb)));
            m0 = fmaf(w, bf2f(hv.x), m0);
            m1 = fmaf(w, bf2f(hv.y), m1);
            m2 = fmaf(w, bf2f(hv.z), m2);
            m3 = fmaf(w, bf2f(hv.w), m3);
            dacc += w;
        }
        #pragma unroll
        for (int o = 16; o < 64; o <<= 1) {
            m0 += __shfl_xor(m0, o, 64);
            m1 += __shfl_xor(m1, o, 64);
            m2 += __shfl_xor(m2, o, 64);
            m3 += __shfl_xor(m3, o, 64);
            dacc += __shfl_xor(dacc, o, 64);
        }
        if (lane < 16) {
            float dg = dacc + 1e-8f;
            ushort4 o4;
            o4.x = f2bf(m0 / dg);
            o4.y = f2bf(m1 / dg);
            o4.z = f2bf(m2 / dg);
            o4.w = f2bf(m3 / dg);
            *(ushort4*)(nb + (size_t)n * 64 + sub * 4) = o4;
        }
    }
}

// MFMA update + residual + LayerNorm. No barriers (per-wave tls), A-fragments
// loaded directly from nb; residual h read as bf16 from ahb.
// MODE 0: fused next-layer gate projection (rewrites ahb/bbuf).
// MODE 1: fused softplus output head -> U.
template <int MODE>
__global__ __launch_bounds__(256) void upd_kernel(
    const ushort_t* __restrict__ nb,
    const ushort_t* __restrict__ u1f, const float* __restrict__ b1,
    const ushort_t* __restrict__ u2f, const float* __restrict__ b2,
    const float* __restrict__ lng, const float* __restrict__ lnb,
    const ushort_t* __restrict__ g1f, const float* __restrict__ gb1,
    ushort_t* __restrict__ ahb, float* __restrict__ bbuf,
    const ushort_t* __restrict__ tuf, const float* __restrict__ tub,
    float* __restrict__ U, int N) {
    __shared__ ushort_t tls[4][16][72];
    const int tid  = threadIdx.x;
    const int lane = tid & 63;
    const int w    = tid >> 6;
    const int m_   = lane & 15;
    const int g    = lane >> 4;
    const int rbase = blockIdx.x * 64;
    const int arow = rbase + w * 16 + m_;
    const bool rowok = arow < N;
    f32x4 acc[4] = {{0,0,0,0},{0,0,0,0},{0,0,0,0},{0,0,0,0}};
    #pragma unroll
    for (int kb = 0; kb < 2; ++kb) {
        bf16x8 a = {0, 0, 0, 0, 0, 0, 0, 0};
        if (rowok) a = *(const bf16x8*)(nb + (size_t)arow * 64 + kb * 32 + g * 8);
        #pragma unroll
        for (int nt = 0; nt < 4; ++nt) {
            bf16x8 b = *(const bf16x8*)(u1f + (((size_t)nt * 2 + kb) * 64 + lane) * 8);
            acc[nt] = __builtin_amdgcn_mfma_f32_16x16x32_bf16(a, b, acc[nt], 0, 0, 0);
        }
    }
    #pragma unroll
    for (int nt = 0; nt < 4; ++nt) {
        float bb1 = b1[nt * 16 + m_];
        #pragma unroll
        for (int r = 0; r < 4; ++r)
            tls[w][g * 4 + r][nt * 16 + m_] = f2bf(fmaxf(acc[nt][r] + bb1, 0.f));
    }
    f32x4 acc2[4] = {{0,0,0,0},{0,0,0,0},{0,0,0,0},{0,0,0,0}};
    #pragma unroll
    for (int kb = 0; kb < 2; ++kb) {
        bf16x8 a2 = *(const bf16x8*)&tls[w][m_][kb * 32 + g * 8];
        #pragma unroll
        for (int nt = 0; nt < 4; ++nt) {
            bf16x8 b = *(const bf16x8*)(u2f + (((size_t)nt * 2 + kb) * 64 + lane) * 8);
            acc2[nt] = __builtin_amdgcn_mfma_f32_16x16x32_bf16(a2, b, acc2[nt], 0, 0, 0);
        }
    }
    // residual (bf16 h from ahb) + LN in D-layout; hn -> tls for epilogue
    float hn_reg[4][4];   // [r][nt]
    #pragma unroll
    for (int r = 0; r < 4; ++r) {
        const int grow = rbase + w * 16 + g * 4 + r;
        float pre[4];
        float s1 = 0.f, s2 = 0.f;
        #pragma unroll
        for (int nt = 0; nt < 4; ++nt) {
            float hv = (grow < N)
                ? bf2f(ahb[(size_t)grow * 128 + 64 + nt * 16 + m_]) : 0.f;
            pre[nt] = acc2[nt][r] + b2[nt * 16 + m_] + hv;
            s1 += pre[nt];
            s2 += pre[nt] * pre[nt];
        }
        #pragma unroll
        for (int o = 1; o < 16; o <<= 1) {
            s1 += __shfl_xor(s1, o, 64);
            s2 += __shfl_xor(s2, o, 64);
        }
        float mean = s1 * (1.0f / 64.0f);
        float var  = s2 * (1.0f / 64.0f) - mean * mean;
        float rinv = rsqrtf(var + 1e-5f);
        #pragma unroll
        for (int nt = 0; nt < 4; ++nt) {
            float hn = (pre[nt] - mean) * rinv * lng[nt * 16 + m_] + lnb[nt * 16 + m_];
            hn_reg[r][nt] = hn;
            tls[w][g * 4 + r][nt * 16 + m_] = f2bf(hn);
        }
    }
    if (MODE == 0) {
        // bf16 h_new into ahb
        #pragma unroll
        for (int nt = 0; nt < 4; ++nt) {
            #pragma unroll
            for (int r = 0; r < 4; ++r) {
                int grow = rbase + w * 16 + g * 4 + r;
                if (grow < N)
                    ahb[(size_t)grow * 128 + 64 + nt * 16 + m_] = f2bf(hn_reg[r][nt]);
            }
        }
        // gate projection for next layer
        f32x4 accp[8] = {{0,0,0,0},{0,0,0,0},{0,0,0,0},{0,0,0,0},
                         {0,0,0,0},{0,0,0,0},{0,0,0,0},{0,0,0,0}};
        #pragma unroll
        for (int kb = 0; kb < 2; ++kb) {
            bf16x8 a3 = *(const bf16x8*)&tls[w][m_][kb * 32 + g * 8];
            #pragma unroll
            for (int j = 0; j < 8; ++j) {
                bf16x8 b = *(const bf16x8*)(g1f + (((size_t)j * 2 + kb) * 64 + lane) * 8);
                accp[j] = __builtin_amdgcn_mfma_f32_16x16x32_bf16(a3, b, accp[j], 0, 0, 0);
            }
        }
        #pragma unroll
        for (int nt = 0; nt < 4; ++nt) {
            float gbl = gb1[nt * 16 + m_];
            #pragma unroll
            for (int r = 0; r < 4; ++r) {
                int grow = rbase + w * 16 + g * 4 + r;
                if (grow < N) {
                    ahb[(size_t)grow * 128 + nt * 16 + m_] = f2bf(accp[nt][r] + gbl);
                    bbuf[(size_t)grow * 64 + nt * 16 + m_] = accp[nt + 4][r];
                }
            }
        }
    } else {
        // output head: U = softplus(h @ toU_w + toU_b), K = 32
        f32x4 accu[2] = {{0,0,0,0},{0,0,0,0}};
        #pragma unroll
        for (int kb = 0; kb < 2; ++kb) {
            bf16x8 a3 = *(const bf16x8*)&tls[w][m_][kb * 32 + g * 8];
            #pragma unroll
            for (int nt = 0; nt < 2; ++nt) {
                bf16x8 b = *(const bf16x8*)(tuf + (((size_t)nt * 2 + kb) * 64 + lane) * 8);
                accu[nt] = __builtin_amdgcn_mfma_f32_16x16x32_bf16(a3, b, accu[nt], 0, 0, 0);
            }
        }
        #pragma unroll
        for (int nt = 0; nt < 2; ++nt) {
            float tb = tub[nt * 16 + m_];
            #pragma unroll
            for (int r = 0; r < 4; ++r) {
                int grow = rbase + w * 16 + g * 4 + r;
                if (grow < N) {
                    float av = accu[nt][r] + tb;
                    float sp = av > 0.f ? av + log1pf(__expf(-av))
                                        : log1pf(__expf(av));
                    U[(size_t)grow * 32 + nt * 16 + m_] = sp;
                }
            }
        }
    }
}

extern "C" void kernel_launch(void* const* d_in, const int* in_sizes, int n_in,
                              void* d_out, int out_size, void* d_ws, size_t ws_size,
                              hipStream_t stream) {
    const float* x       = (const float*)d_in[0];
    const int*   src     = (const int*)d_in[1];
    const int*   dst     = (const int*)d_in[2];
    const float* base_w  = (const float*)d_in[3];
    const float* enc_w1  = (const float*)d_in[4];
    const float* enc_b1  = (const float*)d_in[5];
    const float* enc_w2  = (const float*)d_in[6];
    const float* enc_b2  = (const float*)d_in[7];
    const float* gate_w1 = (const float*)d_in[8];
    const float* gate_b1 = (const float*)d_in[9];
    const float* gate_w2 = (const float*)d_in[10];
    const float* gate_b2 = (const float*)d_in[11];
    const float* upd_w1  = (const float*)d_in[12];
    const float* upd_b1  = (const float*)d_in[13];
    const float* upd_w2  = (const float*)d_in[14];
    const float* upd_b2  = (const float*)d_in[15];
    const float* ln_g    = (const float*)d_in[16];
    const float* ln_b    = (const float*)d_in[17];
    const float* rho_raw = (const float*)d_in[18];
    const float* toU_w   = (const float*)d_in[19];
    const float* toU_b   = (const float*)d_in[20];

    const int N = in_sizes[18];          // 50000
    const int E = in_sizes[1];           // 800000
    const int nsb = (N + 255) / 256;     // scan blocks

    // workspace layout (float units)
    float* ws  = (float*)d_ws;
    size_t off = 0;
    ushort_t* ahb = (ushort_t*)(ws + off); off += (size_t)N * 64;  // N*128 ushort
    float* bb  = ws + off; off += (size_t)N * 64;
    ushort_t* nb = (ushort_t*)(ws + off); off += (size_t)N * 32;   // N*64 ushort
    int* row_ptr = (int*)(ws + off); off += (size_t)((N + 1 + 3) & ~3);
    int* cnt     = (int*)(ws + off); off += (size_t)((N + 3) & ~3);
    int* bsum    = (int*)(ws + off); off += (size_t)((nsb + 3) & ~3);
    int* rank    = (int*)(ws + off); off += (size_t)E;
    int2* recs   = (int2*)(ws + off); off += (size_t)E * 2;   // (s,c)
    ushort_t* w1f = (ushort_t*)(ws + off); off += 8192;       // 16384 ushort
    ushort_t* w2f = (ushort_t*)(ws + off); off += 2048;       // 4096 ushort
    ushort_t* g1f = (ushort_t*)(ws + off); off += 4096;       // 8192 ushort
    ushort_t* u1f = (ushort_t*)(ws + off); off += 4096;       // 8192 ushort
    ushort_t* u2f = (ushort_t*)(ws + off); off += 4096;       // 8192 ushort
    ushort_t* tuf = (ushort_t*)(ws + off); off += 1024;       // 2048 ushort

    pack_kernel<<<64, 256, 0, stream>>>(enc_w1, enc_w2, gate_w1, upd_w1, upd_w2,
                                        toU_w, w1f, w2f, g1f, u1f, u2f, tuf);
    const int nblk64 = (N + 63) / 64;
    enc_kernel<<<nblk64, 256, 0, stream>>>(x, w1f, enc_b1, w2f, enc_b2,
                                           g1f, gate_b1, ahb, bb, N);

    // CSR build: rank-hist -> hierarchical scan -> atomic-free scatter
    hipMemsetAsync(cnt, 0, (size_t)N * sizeof(int), stream);
    hist_kernel<<<(E + 255) / 256, 256, 0, stream>>>(dst, cnt, rank, E);
    scan1_kernel<<<nsb, 256, 0, stream>>>(cnt, bsum, N);
    scan2_kernel<<<1, 1024, 0, stream>>>(bsum, nsb);
    scan3_kernel<<<nsb, 256, 0, stream>>>(cnt, bsum, row_ptr, N);
    scatter_kernel<<<(E + 255) / 256, 256, 0, stream>>>(src, dst, base_w, rho_raw,
                                                        row_ptr, rank, recs, E);

    // layer 0: gateagg -> upd<0> (proj for layer 1, rewrites ahb/bb)
    gateagg_kernel<<<2048, 256, 0, stream>>>(row_ptr, recs, ahb, bb,
                                             gate_w2, gate_b2, nb, N);
    upd_kernel<0><<<nblk64, 256, 0, stream>>>(
        nb, u1f, upd_b1, u2f, upd_b2, ln_g, ln_b,
        g1f, gate_b1, ahb, bb, tuf, toU_b, (float*)d_out, N);

    // layer 1: gateagg -> upd<1> (softplus head -> d_out)
    gateagg_kernel<<<2048, 256, 0, stream>>>(row_ptr, recs, ahb, bb,
                                             gate_w2, gate_b2, nb, N);
    upd_kernel<1><<<nblk64, 256, 0, stream>>>(
        nb, u1f + 4096, upd_b1 + 64, u2f + 4096, upd_b2 + 64,
        ln_g + 64, ln_b + 64,
        g1f, gate_b1, ahb, bb, tuf, toU_b, (float*)d_out, N);
}

// Round 19
// 199.977 us; speedup vs baseline: 1.0666x; 1.0666x over previous
//
#include <hip/hip_runtime.h>
#include <math.h>

// ---------------------------------------------------------------------------
// StageA GNN: pack -> MFMA-enc(+proj0) -> CSR -> L x (gateagg -> MFMA-upd
// (+proj1 | +outhead)).
// R19: enc/upd re-decomposed for 4x wave parallelism: block = 16 rows,
// 4 waves, wave w owns the 16-col output tile nt=w. Grid 782 -> 3125 blocks
// (was 3 waves/SIMD -- latency-bound at ~44us each regardless of structure,
// proven by R18's null result). LN = 2-stage cross-wave reduce. All epilogue
// stores staged in LDS -> single coalesced vector statements.
// ---------------------------------------------------------------------------

typedef unsigned short ushort_t;
typedef __attribute__((ext_vector_type(8))) short bf16x8;
typedef __attribute__((ext_vector_type(4))) float f32x4;

__device__ __forceinline__ float bf2f(ushort_t u) {
    return __uint_as_float(((unsigned int)u) << 16);
}
__device__ __forceinline__ ushort_t f2bf(float f) {
    unsigned int x = __float_as_uint(f);
    unsigned int lsb = (x >> 16) & 1u;
    x += 0x7fffu + lsb;                 // round-to-nearest-even
    return (ushort_t)(x >> 16);
}

// pack all weights into MFMA B-fragment order (bf16).
// fragment: elem i of lane l = B[k = kb*32 + (l>>4)*8 + i][n = nt*16 + (l&15)]
__global__ __launch_bounds__(256) void pack_kernel(
    const float* __restrict__ w1, const float* __restrict__ w2,
    const float* __restrict__ gw1, const float* __restrict__ uw1,
    const float* __restrict__ uw2, const float* __restrict__ tw,
    ushort_t* __restrict__ w1f, ushort_t* __restrict__ w2f,
    ushort_t* __restrict__ g1f, ushort_t* __restrict__ u1f,
    ushort_t* __restrict__ u2f, ushort_t* __restrict__ tuf) {
    int t = blockIdx.x * 256 + threadIdx.x;
    if (t < 16384) {   // w1f: nt(4) kb(8) lane(64) i(8)
        int i = t & 7, l = (t >> 3) & 63, kb = (t >> 9) & 7, nt = t >> 12;
        int k = kb * 32 + (l >> 4) * 8 + i, n = nt * 16 + (l & 15);
        w1f[t] = f2bf(w1[(size_t)k * 64 + n]);
    }
    if (t < 4096) {    // w2f: nt(4) kb(2)
        int i = t & 7, l = (t >> 3) & 63, kb = (t >> 9) & 1, nt = t >> 10;
        int k = kb * 32 + (l >> 4) * 8 + i, n = nt * 16 + (l & 15);
        w2f[t] = f2bf(w2[(size_t)k * 64 + n]);
    }
    if (t < 8192) {    // g1f: j(8)=part*4+nt, kb(2); gw1 is [128][64]
        int i = t & 7, l = (t >> 3) & 63, kb = (t >> 9) & 1, j = t >> 10;
        int part = j >> 2, nt = j & 3;
        int k = part * 64 + kb * 32 + (l >> 4) * 8 + i, n = nt * 16 + (l & 15);
        g1f[t] = f2bf(gw1[(size_t)k * 64 + n]);
    }
    if (t < 8192) {    // u1f/u2f: layer(2) nt(4) kb(2)
        int i = t & 7, l = (t >> 3) & 63, kb = (t >> 9) & 1;
        int nt = (t >> 10) & 3, lay = t >> 12;
        int k = kb * 32 + (l >> 4) * 8 + i, n = nt * 16 + (l & 15);
        u1f[t] = f2bf(uw1[(size_t)lay * 4096 + (size_t)k * 64 + n]);
        u2f[t] = f2bf(uw2[(size_t)lay * 4096 + (size_t)k * 64 + n]);
    }
    if (t < 2048) {    // tuf: nt(2) kb(2); toU_w is [64][32]
        int i = t & 7, l = (t >> 3) & 63, kb = (t >> 9) & 1, nt = t >> 10;
        int k = kb * 32 + (l >> 4) * 8 + i, n = nt * 16 + (l & 15);
        tuf[t] = f2bf(tw[(size_t)k * 32 + n]);
    }
}

// MFMA encoder + fused layer-0 gate projection. Block = 16 rows, 4 waves,
// wave w owns the 16-col tile nt=w (proj: tiles j=2w, 2w+1).
__global__ __launch_bounds__(256) void enc_kernel(
    const float* __restrict__ x, const ushort_t* __restrict__ w1f,
    const float* __restrict__ b1, const ushort_t* __restrict__ w2f,
    const float* __restrict__ b2, const ushort_t* __restrict__ g1f,
    const float* __restrict__ gb1,
    ushort_t* __restrict__ ahb, float* __restrict__ bbuf, int N) {
    __shared__ ushort_t xls[16][264];   // 8448 B
    __shared__ ushort_t tls[16][72];    // 2304 B
    __shared__ ushort_t hls[16][72];    // 2304 B
    __shared__ ushort_t als[16][72];    // 2304 B
    __shared__ float    bls[16][68];    // 4352 B
    const int tid  = threadIdx.x;
    const int lane = tid & 63;
    const int w    = tid >> 6;
    const int m    = lane & 15;
    const int g    = lane >> 4;
    const int rbase = blockIdx.x * 16;
    for (int p = tid; p < 16 * 64; p += 256) {
        int row = p >> 6, k4 = p & 63, grow = rbase + row;
        float4 v = (grow < N) ? *(const float4*)(x + (size_t)grow * 256 + k4 * 4)
                              : make_float4(0.f, 0.f, 0.f, 0.f);
        unsigned int p0 = (unsigned int)f2bf(v.x) | ((unsigned int)f2bf(v.y) << 16);
        unsigned int p1 = (unsigned int)f2bf(v.z) | ((unsigned int)f2bf(v.w) << 16);
        *(uint2*)&xls[row][k4 * 4] = make_uint2(p0, p1);
    }
    __syncthreads();
    f32x4 acc = {0, 0, 0, 0};
    #pragma unroll
    for (int kb = 0; kb < 8; ++kb) {
        bf16x8 a = *(const bf16x8*)&xls[m][kb * 32 + g * 8];
        bf16x8 b = *(const bf16x8*)(w1f + (((size_t)w * 8 + kb) * 64 + lane) * 8);
        acc = __builtin_amdgcn_mfma_f32_16x16x32_bf16(a, b, acc, 0, 0, 0);
    }
    {
        float bb1 = b1[w * 16 + m];
        #pragma unroll
        for (int r = 0; r < 4; ++r)
            tls[g * 4 + r][w * 16 + m] = f2bf(fmaxf(acc[r] + bb1, 0.f));
    }
    __syncthreads();
    f32x4 acc2 = {0, 0, 0, 0};
    #pragma unroll
    for (int kb = 0; kb < 2; ++kb) {
        bf16x8 a2 = *(const bf16x8*)&tls[m][kb * 32 + g * 8];
        bf16x8 b = *(const bf16x8*)(w2f + (((size_t)w * 2 + kb) * 64 + lane) * 8);
        acc2 = __builtin_amdgcn_mfma_f32_16x16x32_bf16(a2, b, acc2, 0, 0, 0);
    }
    {
        float bb2 = b2[w * 16 + m];
        #pragma unroll
        for (int r = 0; r < 4; ++r)
            hls[g * 4 + r][w * 16 + m] = f2bf(fmaxf(acc2[r] + bb2, 0.f));
    }
    __syncthreads();
    {   // coalesced h -> ahb h-part (one statement: 256 threads = 16x16 ushort4)
        int row = tid >> 4, c4 = tid & 15, grow = rbase + row;
        if (grow < N)
            *(ushort4*)(ahb + (size_t)grow * 128 + 64 + c4 * 4) =
                *(const ushort4*)&hls[row][c4 * 4];
    }
    // layer-0 gate projection: tiles j0 = 2w, j1 = 2w+1 of [a|b] = h @ gw1
    f32x4 p0 = {0, 0, 0, 0}, p1 = {0, 0, 0, 0};
    #pragma unroll
    for (int kb = 0; kb < 2; ++kb) {
        bf16x8 a3 = *(const bf16x8*)&hls[m][kb * 32 + g * 8];
        bf16x8 b0 = *(const bf16x8*)(g1f + (((size_t)(2 * w) * 2 + kb) * 64 + lane) * 8);
        bf16x8 b1v = *(const bf16x8*)(g1f + (((size_t)(2 * w + 1) * 2 + kb) * 64 + lane) * 8);
        p0 = __builtin_amdgcn_mfma_f32_16x16x32_bf16(a3, b0, p0, 0, 0, 0);
        p1 = __builtin_amdgcn_mfma_f32_16x16x32_bf16(a3, b1v, p1, 0, 0, 0);
    }
    if (w < 2) {        // a-part tiles (cols 0..63)
        int j0 = 2 * w, j1 = 2 * w + 1;
        float gb0 = gb1[j0 * 16 + m], gb1v = gb1[j1 * 16 + m];
        #pragma unroll
        for (int r = 0; r < 4; ++r) {
            als[g * 4 + r][j0 * 16 + m] = f2bf(p0[r] + gb0);
            als[g * 4 + r][j1 * 16 + m] = f2bf(p1[r] + gb1v);
        }
    } else {            // b-part tiles (cols 64..127 -> bls 0..63)
        int j0 = 2 * w - 4, j1 = 2 * w - 3;
        #pragma unroll
        for (int r = 0; r < 4; ++r) {
            bls[g * 4 + r][j0 * 16 + m] = p0[r];
            bls[g * 4 + r][j1 * 16 + m] = p1[r];
        }
    }
    __syncthreads();
    {   // coalesced a -> ahb a-part, b -> bbuf
        int row = tid >> 4, c4 = tid & 15, grow = rbase + row;
        if (grow < N) {
            *(ushort4*)(ahb + (size_t)grow * 128 + c4 * 4) =
                *(const ushort4*)&als[row][c4 * 4];
            *(float4*)(bbuf + (size_t)grow * 64 + c4 * 4) =
                *(const float4*)&bls[row][c4 * 4];
        }
    }
}

// ---- CSR build ----
__global__ __launch_bounds__(256) void hist_kernel(
    const int* __restrict__ dst, int* __restrict__ cnt,
    int* __restrict__ rank, int E) {
    for (int e = blockIdx.x * blockDim.x + threadIdx.x; e < E;
         e += gridDim.x * blockDim.x)
        rank[e] = atomicAdd(&cnt[dst[e]], 1);
}

__global__ __launch_bounds__(256) void scan1_kernel(
    const int* __restrict__ cnt, int* __restrict__ bsum, int N) {
    __shared__ int red[256];
    int i = blockIdx.x * 256 + threadIdx.x;
    red[threadIdx.x] = (i < N) ? cnt[i] : 0;
    __syncthreads();
    for (int off = 128; off > 0; off >>= 1) {
        if (threadIdx.x < off) red[threadIdx.x] += red[threadIdx.x + off];
        __syncthreads();
    }
    if (threadIdx.x == 0) bsum[blockIdx.x] = red[0];
}

__global__ __launch_bounds__(1024) void scan2_kernel(
    int* __restrict__ bsum, int nb) {
    __shared__ int s[1024];
    int v = (threadIdx.x < nb) ? bsum[threadIdx.x] : 0;
    s[threadIdx.x] = v;
    __syncthreads();
    for (int off = 1; off < 1024; off <<= 1) {
        int t = (threadIdx.x >= off) ? s[threadIdx.x - off] : 0;
        __syncthreads();
        s[threadIdx.x] += t;
        __syncthreads();
    }
    if (threadIdx.x < nb) bsum[threadIdx.x] = s[threadIdx.x] - v;  // exclusive
}

__global__ __launch_bounds__(256) void scan3_kernel(
    const int* __restrict__ cnt, const int* __restrict__ bsum,
    int* __restrict__ row_ptr, int N) {
    __shared__ int s[256];
    int i = blockIdx.x * 256 + threadIdx.x;
    int v = (i < N) ? cnt[i] : 0;
    s[threadIdx.x] = v;
    __syncthreads();
    for (int off = 1; off < 256; off <<= 1) {
        int t = (threadIdx.x >= off) ? s[threadIdx.x - off] : 0;
        __syncthreads();
        s[threadIdx.x] += t;
        __syncthreads();
    }
    if (i < N) row_ptr[i] = bsum[blockIdx.x] + s[threadIdx.x] - v;  // exclusive
    if (i == N - 1) row_ptr[N] = bsum[blockIdx.x] + s[threadIdx.x]; // total
}

// atomic-free scatter: pos = row_ptr[dst] + rank (precomputed in hist)
__global__ __launch_bounds__(256) void scatter_kernel(
    const int* __restrict__ src, const int* __restrict__ dst,
    const float* __restrict__ base_w, const float* __restrict__ rr,
    const int* __restrict__ row_ptr, const int* __restrict__ rank,
    int2* __restrict__ recs, int E) {
    for (int e = blockIdx.x * blockDim.x + threadIdx.x; e < E;
         e += gridDim.x * blockDim.x) {
        int s = src[e], d = dst[e];
        int pos = row_ptr[d] + rank[e];
        float rs = 1.f / (1.f + __expf(-rr[s]));
        float rd = 1.f / (1.f + __expf(-rr[d]));
        float c = base_w[e] * rs * rd;
        recs[pos] = make_int2(s, __float_as_int(c));
    }
}

// fused gate + aggregation (proven R18): wave-per-node, 16-lane group/edge,
// writes normalized bf16 neigh rows (nb).
__global__ __launch_bounds__(256) void gateagg_kernel(
    const int* __restrict__ row_ptr, const int2* __restrict__ recs,
    const ushort_t* __restrict__ ahb, const float* __restrict__ bb,
    const float* __restrict__ gw2, const float* __restrict__ gb2,
    ushort_t* __restrict__ nb, int N) {
    const int lane = threadIdx.x & 63;
    const int sub  = lane & 15;
    const int grp  = lane >> 4;
    const float4 gv = ((const float4*)gw2)[sub];
    const float gb = gb2[0];
    const int wid  = blockIdx.x * (blockDim.x >> 6) + (threadIdx.x >> 6);
    const int nw   = gridDim.x * (blockDim.x >> 6);
    for (int n = wid; n < N; n += nw) {
        const int beg = row_ptr[n], end = row_ptr[n + 1];
        const float4 bv = *(const float4*)(bb + (size_t)n * 64 + sub * 4);
        float m0 = 0.f, m1 = 0.f, m2 = 0.f, m3 = 0.f, dacc = 0.f;
        int i = beg + grp;
        for (; i + 4 < end; i += 8) {
            int2 rA = recs[i];
            int2 rB = recs[i + 4];
            const ushort_t* rowA = ahb + (size_t)rA.x * 128;
            const ushort_t* rowB = ahb + (size_t)rB.x * 128;
            ushort4 avA = *(const ushort4*)(rowA + sub * 4);
            ushort4 hvA = *(const ushort4*)(rowA + 64 + sub * 4);
            ushort4 avB = *(const ushort4*)(rowB + sub * 4);
            ushort4 hvB = *(const ushort4*)(rowB + 64 + sub * 4);
            float tA = fmaxf(bf2f(avA.x) + bv.x, 0.f) * gv.x
                     + fmaxf(bf2f(avA.y) + bv.y, 0.f) * gv.y
                     + fmaxf(bf2f(avA.z) + bv.z, 0.f) * gv.z
                     + fmaxf(bf2f(avA.w) + bv.w, 0.f) * gv.w;
            float tB = fmaxf(bf2f(avB.x) + bv.x, 0.f) * gv.x
                     + fmaxf(bf2f(avB.y) + bv.y, 0.f) * gv.y
                     + fmaxf(bf2f(avB.z) + bv.z, 0.f) * gv.z
                     + fmaxf(bf2f(avB.w) + bv.w, 0.f) * gv.w;
            #pragma unroll
            for (int o = 8; o > 0; o >>= 1) {
                tA += __shfl_xor(tA, o, 64);
                tB += __shfl_xor(tB, o, 64);
            }
            float wA = __int_as_float(rA.y) / (1.f + __expf(-(tA + gb)));
            float wB = __int_as_float(rB.y) / (1.f + __expf(-(tB + gb)));
            m0 = fmaf(wA, bf2f(hvA.x), m0); m0 = fmaf(wB, bf2f(hvB.x), m0);
            m1 = fmaf(wA, bf2f(hvA.y), m1); m1 = fmaf(wB, bf2f(hvB.y), m1);
            m2 = fmaf(wA, bf2f(hvA.z), m2); m2 = fmaf(wB, bf2f(hvB.z), m2);
            m3 = fmaf(wA, bf2f(hvA.w), m3); m3 = fmaf(wB, bf2f(hvB.w), m3);
            dacc += wA + wB;
        }
        if (i < end) {
            int2 r = recs[i];
            const ushort_t* row = ahb + (size_t)r.x * 128;
            ushort4 av = *(const ushort4*)(row + sub * 4);
            ushort4 hv = *(const ushort4*)(row + 64 + sub * 4);
            float t = fmaxf(bf2f(av.x) + bv.x, 0.f) * gv.x
                    + fmaxf(bf2f(av.y) + bv.y, 0.f) * gv.y
                    + fmaxf(bf2f(av.z) + bv.z, 0.f) * gv.z
                    + fmaxf(bf2f(av.w) + bv.w, 0.f) * gv.w;
            #pragma unroll
            for (int o = 8; o > 0; o >>= 1) t += __shfl_xor(t, o, 64);
            float w = __int_as_float(r.y) / (1.f + __expf(-(t + gb)));
            m0 = fmaf(w, bf2f(hv.x), m0);
            m1 = fmaf(w, bf2f(hv.y), m1);
            m2 = fmaf(w, bf2f(hv.z), m2);
            m3 = fmaf(w, bf2f(hv.w), m3);
            dacc += w;
        }
        #pragma unroll
        for (int o = 16; o < 64; o <<= 1) {
            m0 += __shfl_xor(m0, o, 64);
            m1 += __shfl_xor(m1, o, 64);
            m2 += __shfl_xor(m2, o, 64);
            m3 += __shfl_xor(m3, o, 64);
            dacc += __shfl_xor(dacc, o, 64);
        }
        if (lane < 16) {
            float dg = dacc + 1e-8f;
            ushort4 o4;
            o4.x = f2bf(m0 / dg);
            o4.y = f2bf(m1 / dg);
            o4.z = f2bf(m2 / dg);
            o4.w = f2bf(m3 / dg);
            *(ushort4*)(nb + (size_t)n * 64 + sub * 4) = o4;
        }
    }
}

// MFMA update + residual + LayerNorm. Block = 16 rows, 4 waves, wave w owns
// col-tile nt=w. LN: 4-step intra-group shfl reduce -> LDS combine (4 waves).
// MODE 0: fused next-layer gate projection. MODE 1: fused softplus head.
template <int MODE>
__global__ __launch_bounds__(256) void upd_kernel(
    const ushort_t* __restrict__ nb,
    const ushort_t* __restrict__ u1f, const float* __restrict__ b1,
    const ushort_t* __restrict__ u2f, const float* __restrict__ b2,
    const float* __restrict__ lng, const float* __restrict__ lnb,
    const ushort_t* __restrict__ g1f, const float* __restrict__ gb1,
    ushort_t* __restrict__ ahb, float* __restrict__ bbuf,
    const ushort_t* __restrict__ tuf, const float* __restrict__ tub,
    float* __restrict__ U, int N) {
    __shared__ ushort_t xn[16][72];     // neigh bf16
    __shared__ ushort_t hls[16][72];    // residual h bf16
    __shared__ ushort_t tls[16][72];    // t, then h_new
    __shared__ ushort_t als[16][72];    // proj a staging
    __shared__ float    bls[16][68];    // proj b staging
    __shared__ float    sred[16][4][2]; // LN partials
    const int tid  = threadIdx.x;
    const int lane = tid & 63;
    const int w    = tid >> 6;
    const int m_   = lane & 15;
    const int g    = lane >> 4;
    const int rbase = blockIdx.x * 16;
    {   // coalesced stage: neigh + residual h (one statement each)
        int row = tid >> 4, c4 = tid & 15, grow = rbase + row;
        ushort4 z; z.x = z.y = z.z = z.w = 0;
        ushort4 nv = (grow < N) ? *(const ushort4*)(nb + (size_t)grow * 64 + c4 * 4) : z;
        ushort4 hv = (grow < N) ? *(const ushort4*)(ahb + (size_t)grow * 128 + 64 + c4 * 4) : z;
        *(ushort4*)&xn[row][c4 * 4] = nv;
        *(ushort4*)&hls[row][c4 * 4] = hv;
    }
    __syncthreads();
    f32x4 acc = {0, 0, 0, 0};
    #pragma unroll
    for (int kb = 0; kb < 2; ++kb) {
        bf16x8 a = *(const bf16x8*)&xn[m_][kb * 32 + g * 8];
        bf16x8 b = *(const bf16x8*)(u1f + (((size_t)w * 2 + kb) * 64 + lane) * 8);
        acc = __builtin_amdgcn_mfma_f32_16x16x32_bf16(a, b, acc, 0, 0, 0);
    }
    {
        float bb1 = b1[w * 16 + m_];
        #pragma unroll
        for (int r = 0; r < 4; ++r)
            tls[g * 4 + r][w * 16 + m_] = f2bf(fmaxf(acc[r] + bb1, 0.f));
    }
    __syncthreads();
    f32x4 acc2 = {0, 0, 0, 0};
    #pragma unroll
    for (int kb = 0; kb < 2; ++kb) {
        bf16x8 a2 = *(const bf16x8*)&tls[m_][kb * 32 + g * 8];
        bf16x8 b = *(const bf16x8*)(u2f + (((size_t)w * 2 + kb) * 64 + lane) * 8);
        acc2 = __builtin_amdgcn_mfma_f32_16x16x32_bf16(a2, b, acc2, 0, 0, 0);
    }
    // residual + LN partials
    float pre[4];
    {
        float bb2 = b2[w * 16 + m_];
        #pragma unroll
        for (int r = 0; r < 4; ++r) {
            pre[r] = acc2[r] + bb2 + bf2f(hls[g * 4 + r][w * 16 + m_]);
            float s1 = pre[r], s2 = pre[r] * pre[r];
            #pragma unroll
            for (int o = 1; o < 16; o <<= 1) {
                s1 += __shfl_xor(s1, o, 64);
                s2 += __shfl_xor(s2, o, 64);
            }
            if (m_ == 0) {
                sred[g * 4 + r][w][0] = s1;
                sred[g * 4 + r][w][1] = s2;
            }
        }
    }
    __syncthreads();
    {
        float lg = lng[w * 16 + m_], lb = lnb[w * 16 + m_];
        #pragma unroll
        for (int r = 0; r < 4; ++r) {
            int row = g * 4 + r;
            float s1 = (sred[row][0][0] + sred[row][1][0])
                     + (sred[row][2][0] + sred[row][3][0]);
            float s2 = (sred[row][0][1] + sred[row][1][1])
                     + (sred[row][2][1] + sred[row][3][1]);
            float mean = s1 * (1.0f / 64.0f);
            float var  = s2 * (1.0f / 64.0f) - mean * mean;
            float rinv = rsqrtf(var + 1e-5f);
            float hn = (pre[r] - mean) * rinv * lg + lb;
            tls[row][w * 16 + m_] = f2bf(hn);
        }
    }
    __syncthreads();
    if (MODE == 0) {
        {   // coalesced h_new -> ahb h-part
            int row = tid >> 4, c4 = tid & 15, grow = rbase + row;
            if (grow < N)
                *(ushort4*)(ahb + (size_t)grow * 128 + 64 + c4 * 4) =
                    *(const ushort4*)&tls[row][c4 * 4];
        }
        // gate projection for next layer: tiles j = 2w, 2w+1
        f32x4 p0 = {0, 0, 0, 0}, p1 = {0, 0, 0, 0};
        #pragma unroll
        for (int kb = 0; kb < 2; ++kb) {
            bf16x8 a3 = *(const bf16x8*)&tls[m_][kb * 32 + g * 8];
            bf16x8 b0 = *(const bf16x8*)(g1f + (((size_t)(2 * w) * 2 + kb) * 64 + lane) * 8);
            bf16x8 b1v = *(const bf16x8*)(g1f + (((size_t)(2 * w + 1) * 2 + kb) * 64 + lane) * 8);
            p0 = __builtin_amdgcn_mfma_f32_16x16x32_bf16(a3, b0, p0, 0, 0, 0);
            p1 = __builtin_amdgcn_mfma_f32_16x16x32_bf16(a3, b1v, p1, 0, 0, 0);
        }
        if (w < 2) {
            int j0 = 2 * w, j1 = 2 * w + 1;
            float gb0 = gb1[j0 * 16 + m_], gb1v = gb1[j1 * 16 + m_];
            #pragma unroll
            for (int r = 0; r < 4; ++r) {
                als[g * 4 + r][j0 * 16 + m_] = f2bf(p0[r] + gb0);
                als[g * 4 + r][j1 * 16 + m_] = f2bf(p1[r] + gb1v);
            }
        } else {
            int j0 = 2 * w - 4, j1 = 2 * w - 3;
            #pragma unroll
            for (int r = 0; r < 4; ++r) {
                bls[g * 4 + r][j0 * 16 + m_] = p0[r];
                bls[g * 4 + r][j1 * 16 + m_] = p1[r];
            }
        }
        __syncthreads();
        {
            int row = tid >> 4, c4 = tid & 15, grow = rbase + row;
            if (grow < N) {
                *(ushort4*)(ahb + (size_t)grow * 128 + c4 * 4) =
                    *(const ushort4*)&als[row][c4 * 4];
                *(float4*)(bbuf + (size_t)grow * 64 + c4 * 4) =
                    *(const float4*)&bls[row][c4 * 4];
            }
        }
    } else {
        // output head: waves 0,1 compute U tiles nt=w
        if (w < 2) {
            f32x4 au = {0, 0, 0, 0};
            #pragma unroll
            for (int kb = 0; kb < 2; ++kb) {
                bf16x8 a3 = *(const bf16x8*)&tls[m_][kb * 32 + g * 8];
                bf16x8 b = *(const bf16x8*)(tuf + (((size_t)w * 2 + kb) * 64 + lane) * 8);
                au = __builtin_amdgcn_mfma_f32_16x16x32_bf16(a3, b, au, 0, 0, 0);
            }
            float tb = tub[w * 16 + m_];
            #pragma unroll
            for (int r = 0; r < 4; ++r) {
                int grow = rbase + g * 4 + r;
                if (grow < N) {
                    float av = au[r] + tb;
                    float sp = av > 0.f ? av + log1pf(__expf(-av))
                                        : log1pf(__expf(av));
                    U[(size_t)grow * 32 + w * 16 + m_] = sp;
                }
            }
        }
    }
}

extern "C" void kernel_launch(void* const* d_in, const int* in_sizes, int n_in,
                              void* d_out, int out_size, void* d_ws, size_t ws_size,
                              hipStream_t stream) {
    const float* x       = (const float*)d_in[0];
    const int*   src     = (const int*)d_in[1];
    const int*   dst     = (const int*)d_in[2];
    const float* base_w  = (const float*)d_in[3];
    const float* enc_w1  = (const float*)d_in[4];
    const float* enc_b1  = (const float*)d_in[5];
    const float* enc_w2  = (const float*)d_in[6];
    const float* enc_b2  = (const float*)d_in[7];
    const float* gate_w1 = (const float*)d_in[8];
    const float* gate_b1 = (const float*)d_in[9];
    const float* gate_w2 = (const float*)d_in[10];
    const float* gate_b2 = (const float*)d_in[11];
    const float* upd_w1  = (const float*)d_in[12];
    const float* upd_b1  = (const float*)d_in[13];
    const float* upd_w2  = (const float*)d_in[14];
    const float* upd_b2  = (const float*)d_in[15];
    const float* ln_g    = (const float*)d_in[16];
    const float* ln_b    = (const float*)d_in[17];
    const float* rho_raw = (const float*)d_in[18];
    const float* toU_w   = (const float*)d_in[19];
    const float* toU_b   = (const float*)d_in[20];

    const int N = in_sizes[18];          // 50000
    const int E = in_sizes[1];           // 800000
    const int nsb = (N + 255) / 256;     // scan blocks

    // workspace layout (float units)
    float* ws  = (float*)d_ws;
    size_t off = 0;
    ushort_t* ahb = (ushort_t*)(ws + off); off += (size_t)N * 64;  // N*128 ushort
    float* bb  = ws + off; off += (size_t)N * 64;
    ushort_t* nb = (ushort_t*)(ws + off); off += (size_t)N * 32;   // N*64 ushort
    int* row_ptr = (int*)(ws + off); off += (size_t)((N + 1 + 3) & ~3);
    int* cnt     = (int*)(ws + off); off += (size_t)((N + 3) & ~3);
    int* bsum    = (int*)(ws + off); off += (size_t)((nsb + 3) & ~3);
    int* rank    = (int*)(ws + off); off += (size_t)E;
    int2* recs   = (int2*)(ws + off); off += (size_t)E * 2;   // (s,c)
    ushort_t* w1f = (ushort_t*)(ws + off); off += 8192;       // 16384 ushort
    ushort_t* w2f = (ushort_t*)(ws + off); off += 2048;       // 4096 ushort
    ushort_t* g1f = (ushort_t*)(ws + off); off += 4096;       // 8192 ushort
    ushort_t* u1f = (ushort_t*)(ws + off); off += 4096;       // 8192 ushort
    ushort_t* u2f = (ushort_t*)(ws + off); off += 4096;       // 8192 ushort
    ushort_t* tuf = (ushort_t*)(ws + off); off += 1024;       // 2048 ushort

    pack_kernel<<<64, 256, 0, stream>>>(enc_w1, enc_w2, gate_w1, upd_w1, upd_w2,
                                        toU_w, w1f, w2f, g1f, u1f, u2f, tuf);
    const int nblk16 = (N + 15) / 16;
    enc_kernel<<<nblk16, 256, 0, stream>>>(x, w1f, enc_b1, w2f, enc_b2,
                                           g1f, gate_b1, ahb, bb, N);

    // CSR build: rank-hist -> hierarchical scan -> atomic-free scatter
    hipMemsetAsync(cnt, 0, (size_t)N * sizeof(int), stream);
    hist_kernel<<<(E + 255) / 256, 256, 0, stream>>>(dst, cnt, rank, E);
    scan1_kernel<<<nsb, 256, 0, stream>>>(cnt, bsum, N);
    scan2_kernel<<<1, 1024, 0, stream>>>(bsum, nsb);
    scan3_kernel<<<nsb, 256, 0, stream>>>(cnt, bsum, row_ptr, N);
    scatter_kernel<<<(E + 255) / 256, 256, 0, stream>>>(src, dst, base_w, rho_raw,
                                                        row_ptr, rank, recs, E);

    // layer 0: gateagg -> upd<0> (proj for layer 1, rewrites ahb/bb)
    gateagg_kernel<<<2048, 256, 0, stream>>>(row_ptr, recs, ahb, bb,
                                             gate_w2, gate_b2, nb, N);
    upd_kernel<0><<<nblk16, 256, 0, stream>>>(
        nb, u1f, upd_b1, u2f, upd_b2, ln_g, ln_b,
        g1f, gate_b1, ahb, bb, tuf, toU_b, (float*)d_out, N);

    // layer 1: gateagg -> upd<1> (softplus head -> d_out)
    gateagg_kernel<<<2048, 256, 0, stream>>>(row_ptr, recs, ahb, bb,
                                             gate_w2, gate_b2, nb, N);
    upd_kernel<1><<<nblk16, 256, 0, stream>>>(
        nb, u1f + 4096, upd_b1 + 64, u2f + 4096, upd_b2 + 64,
        ln_g + 64, ln_b + 64,
        g1f, gate_b1, ahb, bb, tuf, toU_b, (float*)d_out, N);
}